// Round 1
// baseline (257.025 us; speedup 1.0000x reference)
//
#include <hip/hip_runtime.h>

// Problem constants (match reference)
constexpr int B = 1024, N = 100, C = 256, K = 3;
constexpr int ROWS = B * N;                    // 102400
constexpr int THREADS = 256;
constexpr int LANES_PER_ROW = 16;              // 16 lanes x 16 channels = 256
constexpr int ROWS_PER_BLOCK = THREADS / LANES_PER_ROW;   // 16
constexpr int BLOCKS = ROWS / ROWS_PER_BLOCK;  // 6400, exact
constexpr float LN_EPS = 1e-5f;

typedef float f32x4 __attribute__((ext_vector_type(4)));

// DPP control encodings (per GCN ISA): row ops act within 16-lane rows,
// which exactly match our 16-lane groups (t & 15).
#define DPP_ROW_SHL(n) (0x100 | (n))   // lane i <- lane i+n, out-of-row -> bound
#define DPP_ROW_SHR(n) (0x110 | (n))   // lane i <- lane i-n, out-of-row -> bound
#define DPP_ROW_ROR(n) (0x120 | (n))   // lane i <- lane (i-n) mod 16 (wraps)

template <int CTRL, bool BOUND_ZERO>
__device__ __forceinline__ float fdpp(float x) {
    return __int_as_float(__builtin_amdgcn_update_dpp(
        0, __float_as_int(x), CTRL, 0xF, 0xF, BOUND_ZERO));
}

// Full sum across the 16-lane group, pure VALU (no DS pipe).
__device__ __forceinline__ float rowsum16(float x) {
    x += fdpp<DPP_ROW_ROR(1), false>(x);
    x += fdpp<DPP_ROW_ROR(2), false>(x);
    x += fdpp<DPP_ROW_ROR(4), false>(x);
    x += fdpp<DPP_ROW_ROR(8), false>(x);
    return x;
}

__global__ __launch_bounds__(256) void dydwconv_ln_kernel(
    const float* __restrict__ query,   // [B,N,C]
    const float* __restrict__ value,   // [B,N,C]
    const float* __restrict__ Ww,      // [K,C]
    const float* __restrict__ bw,      // [K]
    const float* __restrict__ gamma,   // [C]
    const float* __restrict__ beta,    // [C]
    float* __restrict__ out)           // [B,N,C]
{
    const int t = threadIdx.x;
    const int l = t & 15;                                    // lane within 16-group
    const int row = blockIdx.x * ROWS_PER_BLOCK + (t >> 4);  // < ROWS (exact division)
    const size_t base = (size_t)row * C;

    // Interleaved chunk layout: lane l, sub-block j owns channels
    // c0 = 4*(j*16 + l) .. c0+3.  Per load instruction the 16 lanes of a
    // group cover one contiguous 256B segment -> perfect coalescing.
    float4 q[4], v[4];
    #pragma unroll
    for (int j = 0; j < 4; ++j) {
        const int c = (j * 16 + l) * 4;
        q[j] = *(const float4*)(query + base + c);
        v[j] = *(const float4*)(value + base + c);
    }

    // Dynamic-kernel dot products: p_k = sum_c q[c] * W[k][c].
    // W is 3 KB, shared by all blocks -> L1-hot; no LDS staging needed.
    float p0 = 0.f, p1 = 0.f, p2 = 0.f;
    #pragma unroll
    for (int j = 0; j < 4; ++j) {
        const int c = (j * 16 + l) * 4;
        const float4 a = *(const float4*)(Ww + c);
        const float4 b = *(const float4*)(Ww + C + c);
        const float4 d = *(const float4*)(Ww + 2 * C + c);
        p0 += q[j].x * a.x + q[j].y * a.y + q[j].z * a.z + q[j].w * a.w;
        p1 += q[j].x * b.x + q[j].y * b.y + q[j].z * b.z + q[j].w * b.w;
        p2 += q[j].x * d.x + q[j].y * d.y + q[j].z * d.z + q[j].w * d.w;
    }
    p0 = rowsum16(p0);
    p1 = rowsum16(p1);
    p2 = rowsum16(p2);
    const float w0 = p0 + bw[0];
    const float w1 = p1 + bw[1];
    const float w2 = p2 + bw[2];

    const bool is_l0  = (l == 0);
    const bool is_l15 = (l == 15);

    // out[c] = v[c-1]*w0 + v[c]*w1 + v[c+1]*w2   (zero-padded ends)
    // Halos via DPP; j-block seams fixed with row rotations:
    //   vleft  lane0  needs v[j-1].w of lane15 -> ROW_ROR(1)
    //   vright lane15 needs v[j+1].x of lane0  -> ROW_ROR(15)
    float4 o[4];
    float s = 0.f, ss = 0.f;
    #pragma unroll
    for (int j = 0; j < 4; ++j) {
        float vl = fdpp<DPP_ROW_SHR(1), true>(v[j].w);   // lane0 -> 0
        if (j > 0) {
            const float wrap = fdpp<DPP_ROW_ROR(1), false>(v[j - 1].w);
            vl = is_l0 ? wrap : vl;
        }
        float vr = fdpp<DPP_ROW_SHL(1), true>(v[j].x);   // lane15 -> 0
        if (j < 3) {
            const float wrap = fdpp<DPP_ROW_ROR(15), false>(v[j + 1].x);
            vr = is_l15 ? wrap : vr;
        }
        o[j].x = vl     * w0 + v[j].x * w1 + v[j].y * w2;
        o[j].y = v[j].x * w0 + v[j].y * w1 + v[j].z * w2;
        o[j].z = v[j].y * w0 + v[j].z * w1 + v[j].w * w2;
        o[j].w = v[j].z * w0 + v[j].w * w1 + vr     * w2;
        s  += (o[j].x + o[j].y) + (o[j].z + o[j].w);
        ss += o[j].x * o[j].x + o[j].y * o[j].y
            + o[j].z * o[j].z + o[j].w * o[j].w;
    }
    s  = rowsum16(s);
    ss = rowsum16(ss);
    const float mu  = s * (1.0f / C);
    const float var = ss * (1.0f / C) - mu * mu;
    const float inv = rsqrtf(var + LN_EPS);

    #pragma unroll
    for (int j = 0; j < 4; ++j) {
        const int c = (j * 16 + l) * 4;
        const float4 g  = *(const float4*)(gamma + c);
        const float4 bt = *(const float4*)(beta + c);
        f32x4 r;
        r.x = (o[j].x - mu) * inv * g.x + bt.x;
        r.y = (o[j].y - mu) * inv * g.y + bt.y;
        r.z = (o[j].z - mu) * inv * g.z + bt.z;
        r.w = (o[j].w - mu) * inv * g.w + bt.w;
        // out is never re-read: non-temporal store keeps inputs resident in L3
        __builtin_nontemporal_store(r, (f32x4*)(out + base + c));
    }
}

extern "C" void kernel_launch(void* const* d_in, const int* in_sizes, int n_in,
                              void* d_out, int out_size, void* d_ws, size_t ws_size,
                              hipStream_t stream) {
    const float* query = (const float*)d_in[0];
    const float* value = (const float*)d_in[1];
    const float* Ww    = (const float*)d_in[2];
    const float* bw    = (const float*)d_in[3];
    const float* gamma = (const float*)d_in[4];
    const float* beta  = (const float*)d_in[5];
    float* outp = (float*)d_out;

    dydwconv_ln_kernel<<<BLOCKS, THREADS, 0, stream>>>(
        query, value, Ww, bw, gamma, beta, outp);
}